// Round 11
// baseline (298.199 us; speedup 1.0000x reference)
//
#include <hip/hip_runtime.h>
#include <math.h>

typedef float vf4 __attribute__((ext_vector_type(4)));

constexpr int T = 8192;
constexpr int D = 128;
constexpr int N = 32;
constexpr int L = 32;            // chunk length
constexpr int LOG2L = 5;         // log2(L)
constexpr int K = T / L;         // 256 chunks
constexpr int S = N * D;         // 4096 state elements
constexpr int S4 = S / 4;        // 1024 float4 states
constexpr int D4 = D / 4;        // 32
constexpr int OSTRIDE4 = (2 * N * D) / 4;  // 2048 float4 per output time-row

// k2 segmented-scan geometry (round-4 measured-good): 32 blocks x
// (32 cols x 8 segs x 32 chunks).
constexpr int SEG  = 8;          // segments per column
constexpr int CPS  = K / SEG;    // 32 chunks per segment
constexpr int LOG2CPS = 5;
constexpr int COLS = 32;         // columns per block (COLS*SEG = 256 threads)

__device__ __forceinline__ float fast_sqrt(float x) {
    float r;
    asm("v_sqrt_f32 %0, %1" : "=v"(r) : "v"(x));
    return r;
}

// ---------------------------------------------------------------------------
// k1: per (chunk k, state s4), walk L steps of x computing H-free summaries:
//   q (=c_a): chunk-local EMA   q' = q + a*(x - q)          (q0 = 0)
//   A:        A' = b*(A + a*p^2),  p = x - q (pre-update q)
//   P:        sum of p
// c_v(H) = A - 2*(a*b^L)*P*H + b^L(1-b^L)*H^2 exactly.
// (byte-identical to the measured 293.5 us round-4 kernel)
// ---------------------------------------------------------------------------
__global__ __launch_bounds__(256) void k1_summaries(
    const vf4* __restrict__ x, const vf4* __restrict__ alpha,
    vf4* __restrict__ c_a, vf4* __restrict__ cA, vf4* __restrict__ cP)
{
    int gid = blockIdx.x * 256 + threadIdx.x;   // [0, K*S4)
    int k   = gid >> 10;                        // gid / S4
    int s4  = gid & (S4 - 1);
    int d4  = s4 & (D4 - 1);

    vf4 a = alpha[s4];
    vf4 b = 1.0f - a;
    vf4 q = {0.f, 0.f, 0.f, 0.f};
    vf4 A = {0.f, 0.f, 0.f, 0.f};
    vf4 P = {0.f, 0.f, 0.f, 0.f};
    const vf4* xp = x + (size_t)k * L * D4 + d4;
#pragma unroll 8
    for (int i = 0; i < L; ++i) {
        vf4 xv = xp[(size_t)i * D4];
        vf4 p  = xv - q;          // p uses q BEFORE update
        P += p;
        A = b * (A + (a * p) * p);
        q = q + a * p;
    }
    c_a[gid] = q;
    cA[gid]  = A;
    cP[gid]  = P;
}

// ---------------------------------------------------------------------------
// k2: in-block segmented scan (round-4 measured-good). Emits h_a_start
// (in-place over c_a), h_v_start (clamped >=0, in-place over cA), and both
// output tails. Single-thread ownership of every (chunk,s4) index in every
// pass => in-place safe; cross-thread state only crosses __syncthreads.
// ---------------------------------------------------------------------------
__global__ __launch_bounds__(256) void k2_scan(
    const vf4* __restrict__ h_a0, const vf4* __restrict__ h_sd0,
    const vf4* __restrict__ alpha,
    vf4* __restrict__ buf0,          // in: c_a   out: h_a_start
    vf4* __restrict__ buf1,          // in: cA    out: h_v_start
    const vf4* __restrict__ buf2,    // cP
    float* __restrict__ out)
{
    __shared__ vf4 Cagg[SEG][COLS];
    __shared__ vf4 Vagg[SEG][COLS];

    int t   = threadIdx.x;
    int col = t & (COLS - 1);
    int kg  = t >> 5;                        // segment index [0, SEG)
    int s4  = blockIdx.x * COLS + col;       // [0, S4)
    int kbase = kg * CPS;

    vf4 a = alpha[s4];
    vf4 b = 1.0f - a;
    vf4 bl = b;
#pragma unroll
    for (int i = 0; i < LOG2L; ++i) bl *= bl;   // b^L (per-chunk multiplier)
    vf4 M = bl;
#pragma unroll
    for (int i = 0; i < LOG2CPS; ++i) M *= M;   // bl^CPS (per-segment mult)
    vf4 Cq = bl * (1.0f - bl);
    vf4 Bc = a * bl;

    // pass 1: segment aggregate of c_a
    vf4 C = {0.f, 0.f, 0.f, 0.f};
#pragma unroll 4
    for (int j = 0; j < CPS; ++j)
        C = bl * C + buf0[(size_t)(kbase + j) * S4 + s4];
    Cagg[kg][col] = C;
    __syncthreads();

    vf4 H = h_a0[s4];
    for (int g = 0; g < kg; ++g) H = M * H + Cagg[g][col];

    // pass 2: emit h_a_start; aggregate c_v
    vf4 Vg = {0.f, 0.f, 0.f, 0.f};
#pragma unroll 4
    for (int j = 0; j < CPS; ++j) {
        size_t idx = (size_t)(kbase + j) * S4 + s4;
        vf4 ca = buf0[idx];
        vf4 Ak = buf1[idx];
        vf4 Pk = buf2[idx];
        buf0[idx] = H;                          // h_a_start (pre-update)
        vf4 cv = Ak - 2.0f * ((Bc * Pk) * H) + Cq * (H * H);
        Vg = bl * Vg + cv;
        H  = bl * H + ca;
    }
    Vagg[kg][col] = Vg;
    if (kg == SEG - 1) {                        // H is hN_a
        ((vf4*)(out + (size_t)T * 2 * N * D))[s4] = H;
    }
    __syncthreads();

    vf4 sdv = h_sd0[s4];
    vf4 V = sdv * sdv;
    for (int g = 0; g < kg; ++g) V = M * V + Vagg[g][col];

    // pass 3: emit h_v_start (clamped >= 0)
#pragma unroll 4
    for (int j = 0; j < CPS; ++j) {
        size_t idx = (size_t)(kbase + j) * S4 + s4;
        vf4 Hk = buf0[idx];                     // h_a_start (just written)
        vf4 Ak = buf1[idx];
        vf4 Pk = buf2[idx];
        vf4 Vc;
#pragma unroll
        for (int jj = 0; jj < 4; ++jj) Vc[jj] = fmaxf(V[jj], 0.f);
        buf1[idx] = Vc;                         // h_v_start (pre-update)
        vf4 cv = Ak - 2.0f * ((Bc * Pk) * Hk) + Cq * (Hk * Hk);
        V = bl * Vc + cv;
    }
    if (kg == SEG - 1) {                        // V is hN_v
        vf4 r;
#pragma unroll
        for (int jj = 0; jj < 4; ++jj) r[jj] = fast_sqrt(fmaxf(V[jj], 0.f));
        ((vf4*)(out + (size_t)T * 2 * N * D))[S4 + s4] = r;
    }
}

// ---------------------------------------------------------------------------
// k3_rows: ROW-CONTIGUOUS output walk. One block per chunk; each block owns
// ALL 4096 states (4 vf4 per thread, in registers) and walks its 32
// timesteps writing FULL 32 KB output rows sequentially -> each block emits
// 1 MB of strictly contiguous stores (the fillBuffer-proven access pattern),
// replacing the old 8KB-strided 1KB-granule scatter. Plain cached stores
// (the 6.5 TB/s evidence is for cached sequential writes; fill dispatches
// sustain it at ~10% occupancy, so 1 block/CU here is not a limiter).
// x amplification also drops 32x: each x row is read by exactly one block
// (one load per thread per t; (tid+256j)&31 == tid&31 for all 4 j-slots).
// ---------------------------------------------------------------------------
__global__ __launch_bounds__(256) void k3_rows(
    const vf4* __restrict__ x, const vf4* __restrict__ alpha,
    const vf4* __restrict__ h_a_start, const vf4* __restrict__ h_v_start,
    vf4* __restrict__ out)
{
    const int k   = blockIdx.x;              // chunk [0, K)
    const int tid = threadIdx.x;             // [0, 256)
    const int d4  = tid & (D4 - 1);          // same for all 4 j-slots

    vf4 a[4], b[4], h[4], v[4];
#pragma unroll
    for (int j = 0; j < 4; ++j) {
        int s4 = tid + 256 * j;
        a[j] = alpha[s4];
        b[j] = 1.0f - a[j];
        h[j] = h_a_start[(size_t)k * S4 + s4];
        v[j] = h_v_start[(size_t)k * S4 + s4];   // >= 0 (clamped in k2)
    }

    const vf4* xp   = x + (size_t)k * L * D4 + d4;
    vf4*       orow = out + (size_t)k * L * OSTRIDE4;

    for (int i = 0; i < L; ++i) {
        vf4 xv = xp[(size_t)i * D4];
#pragma unroll
        for (int j = 0; j < 4; ++j) {
            vf4 dx  = xv - h[j];         // uses OLD h (matches reference)
            vf4 adx = a[j] * dx;
            v[j] = b[j] * (v[j] + adx * dx);
            h[j] = h[j] + adx;
            vf4 r;
#pragma unroll
            for (int jj = 0; jj < 4; ++jj) r[jj] = fast_sqrt(v[j][jj]);
            orow[tid + 256 * j]        = h[j];   // avg half of the row
            orow[1024 + tid + 256 * j] = r;      // sd  half of the row
        }
        orow += OSTRIDE4;                // next 32 KB time-row
    }
}

// ---------------------------------------------------------------------------
extern "C" void kernel_launch(void* const* d_in, const int* in_sizes, int n_in,
                              void* d_out, int out_size, void* d_ws, size_t ws_size,
                              hipStream_t stream) {
    const vf4* x     = (const vf4*)d_in[0];   // (T, D) fp32
    const vf4* h_a0  = (const vf4*)d_in[1];   // (N, D)
    const vf4* h_sd0 = (const vf4*)d_in[2];   // (N, D)
    const vf4* alpha = (const vf4*)d_in[3];   // (N, D)
    float* out = (float*)d_out;               // (T,2N,D) + hN_a (N,D) + hN_sd (N,D)
    float* ws  = (float*)d_ws;

    // workspace: 3 arrays of K*S floats = 4 MB each (12 MB total).
    // buf0: c_a -> h_a_start (in-place in k2); buf1: cA -> h_v_start; buf2: cP.
    vf4* buf0 = (vf4*)(ws + 0 * (size_t)K * S);
    vf4* buf1 = (vf4*)(ws + 1 * (size_t)K * S);
    vf4* buf2 = (vf4*)(ws + 2 * (size_t)K * S);

    dim3 blk(256);

    k1_summaries<<<dim3(K * S4 / 256), blk, 0, stream>>>(x, alpha, buf0, buf1, buf2);
    k2_scan<<<dim3(S4 / COLS), blk, 0, stream>>>(h_a0, h_sd0, alpha,
                                                 buf0, buf1, buf2, out);
    k3_rows<<<dim3(K), blk, 0, stream>>>(x, alpha, buf0, buf1, (vf4*)out);
}

// Round 15
// 289.575 us; speedup vs baseline: 1.0298x; 1.0298x over previous
//
#include <hip/hip_runtime.h>
#include <math.h>

typedef float vf4 __attribute__((ext_vector_type(4)));

constexpr int T = 8192;
constexpr int D = 128;
constexpr int N = 32;
constexpr int L = 32;            // chunk length
constexpr int LOG2L = 5;         // log2(L)
constexpr int K = T / L;         // 256 chunks
constexpr int S = N * D;         // 4096 state elements
constexpr int S4 = S / 4;        // 1024 float4 states
constexpr int D4 = D / 4;        // 32
constexpr int OSTRIDE4 = (2 * N * D) / 4;  // 2048 float4 per output time-row

// kA geometry: 256 blocks x 256 threads; block owns COLS=4 state columns
// across ALL K chunks. Thread (col, kg) walks CPS=4 chunks of x.
constexpr int COLS = 4;          // columns per block
constexpr int SEG  = 64;         // segments per column (threads/COLS)
constexpr int CPS  = K / SEG;    // 4 chunks per segment
constexpr int LOG2CPS = 2;

__device__ __forceinline__ float fast_sqrt(float x) {
    float r;
    asm("v_sqrt_f32 %0, %1" : "=v"(r) : "v"(x));
    return r;
}

// ---------------------------------------------------------------------------
// kA: fused summaries + scan (replaces k1+k2; no global summary round-trip).
// Per thread (col, kg): walk its CPS chunks of x computing the H-free chunk
// summaries   q: chunk-local EMA;  A: sum b^(L-i) a p^2;  P: sum p
// (p = x - q, pre-update q), stash them in LDS, and fold the segment
// aggregate C on the fly. Then the proven 3-pass segmented scan runs out of
// LDS:  c_v(H) = A - 2(a b^L P) H + b^L(1-b^L) H^2 exactly.
// pass2 emits h_a_start; pass3 recomputes H by the SAME op sequence
// (bit-identical) and emits h_v_start clamped >= 0. Tails from kg==SEG-1.
// Global traffic: read x (L2-resident 4 MB) + write 2 x 4 MB h-starts.
// LDS: 56 KB/block (2 blocks/CU); wave stores are 16 B/lane contiguous
// (col is the fast axis) => 2-lane/bank aliasing, conflict-free.
// ---------------------------------------------------------------------------
__global__ __launch_bounds__(256) void kA_sumscan(
    const vf4* __restrict__ x, const vf4* __restrict__ h_a0,
    const vf4* __restrict__ h_sd0, const vf4* __restrict__ alpha,
    vf4* __restrict__ h_a_start, vf4* __restrict__ h_v_start,
    float* __restrict__ out)
{
    __shared__ vf4 Qs[K][COLS];          // 16 KB
    __shared__ vf4 As[K][COLS];          // 16 KB
    __shared__ vf4 Ps[K][COLS];          // 16 KB
    __shared__ vf4 Cagg[SEG][COLS];      //  4 KB
    __shared__ vf4 Vagg[SEG][COLS];      //  4 KB

    const int t   = threadIdx.x;
    const int col = t & (COLS - 1);
    const int kg  = t >> 2;                  // segment index [0, SEG)
    const int s4  = blockIdx.x * COLS + col; // state column [0, S4)
    const int d4  = s4 & (D4 - 1);

    vf4 a = alpha[s4];
    vf4 b = 1.0f - a;
    vf4 bl = b;
#pragma unroll
    for (int i = 0; i < LOG2L; ++i) bl *= bl;   // b^L (per-chunk multiplier)
    vf4 M = bl;
#pragma unroll
    for (int i = 0; i < LOG2CPS; ++i) M *= M;   // bl^CPS (per-segment mult)
    vf4 Cq = bl * (1.0f - bl);
    vf4 Bc = a * bl;

    // ---- pass 0: x-walk; compute q/A/P per owned chunk; stash in LDS ----
    vf4 C = {0.f, 0.f, 0.f, 0.f};
    for (int kk = 0; kk < CPS; ++kk) {
        const int kglob = kg * CPS + kk;
        const vf4* xp = x + (size_t)kglob * L * D4 + d4;
        vf4 q = {0.f, 0.f, 0.f, 0.f};
        vf4 A = {0.f, 0.f, 0.f, 0.f};
        vf4 P = {0.f, 0.f, 0.f, 0.f};
#pragma unroll 8
        for (int i = 0; i < L; ++i) {
            vf4 xv = xp[(size_t)i * D4];
            vf4 p  = xv - q;          // p uses q BEFORE update
            P += p;
            A = b * (A + (a * p) * p);
            q = q + a * p;
        }
        Qs[kglob][col] = q;
        As[kglob][col] = A;
        Ps[kglob][col] = P;
        C = bl * C + q;               // segment aggregate of c_a
    }
    Cagg[kg][col] = C;
    __syncthreads();

    // fold h_a start for this segment
    vf4 H = h_a0[s4];
    for (int g = 0; g < kg; ++g) H = M * H + Cagg[g][col];

    // ---- pass 2: emit h_a_start; aggregate c_v ----
    vf4 Vg = {0.f, 0.f, 0.f, 0.f};
    for (int kk = 0; kk < CPS; ++kk) {
        const int kglob = kg * CPS + kk;
        vf4 ca = Qs[kglob][col];
        vf4 Ak = As[kglob][col];
        vf4 Pk = Ps[kglob][col];
        h_a_start[(size_t)kglob * S4 + s4] = H;     // pre-update
        vf4 cv = Ak - 2.0f * ((Bc * Pk) * H) + Cq * (H * H);
        Vg = bl * Vg + cv;
        H  = bl * H + ca;
    }
    Vagg[kg][col] = Vg;
    if (kg == SEG - 1) {                            // H is hN_a
        ((vf4*)(out + (size_t)T * 2 * N * D))[s4] = H;
    }
    __syncthreads();

    // fold h_v start for this segment
    vf4 sdv = h_sd0[s4];
    vf4 V = sdv * sdv;
    for (int g = 0; g < kg; ++g) V = M * V + Vagg[g][col];

    // ---- pass 3: emit h_v_start (clamped >= 0); H recomputed bit-exact ----
    vf4 H2 = h_a0[s4];
    for (int g = 0; g < kg; ++g) H2 = M * H2 + Cagg[g][col];
    for (int kk = 0; kk < CPS; ++kk) {
        const int kglob = kg * CPS + kk;
        vf4 ca = Qs[kglob][col];
        vf4 Ak = As[kglob][col];
        vf4 Pk = Ps[kglob][col];
        vf4 Vc;
#pragma unroll
        for (int jj = 0; jj < 4; ++jj) Vc[jj] = fmaxf(V[jj], 0.f);
        h_v_start[(size_t)kglob * S4 + s4] = Vc;    // pre-update
        vf4 cv = Ak - 2.0f * ((Bc * Pk) * H2) + Cq * (H2 * H2);
        V  = bl * Vc + cv;
        H2 = bl * H2 + ca;
    }
    if (kg == SEG - 1) {                            // V is hN_v
        vf4 r;
#pragma unroll
        for (int jj = 0; jj < 4; ++jj) r[jj] = fast_sqrt(fmaxf(V[jj], 0.f));
        ((vf4*)(out + (size_t)T * 2 * N * D))[S4 + s4] = r;
    }
}

// ---------------------------------------------------------------------------
// k3_rows: ROW-CONTIGUOUS output walk (byte-identical to the round-11
// measured kernel). One block per chunk; each block owns ALL 4096 states
// (4 vf4/thread in registers) and walks its 32 timesteps writing full 32 KB
// output rows sequentially -> 1 MB contiguous per block. Plain cached
// stores. (tid+256j)&31 == tid&31, so one x load serves all 4 j-slots.
// ---------------------------------------------------------------------------
__global__ __launch_bounds__(256) void k3_rows(
    const vf4* __restrict__ x, const vf4* __restrict__ alpha,
    const vf4* __restrict__ h_a_start, const vf4* __restrict__ h_v_start,
    vf4* __restrict__ out)
{
    const int k   = blockIdx.x;              // chunk [0, K)
    const int tid = threadIdx.x;             // [0, 256)
    const int d4  = tid & (D4 - 1);          // same for all 4 j-slots

    vf4 a[4], b[4], h[4], v[4];
#pragma unroll
    for (int j = 0; j < 4; ++j) {
        int s4 = tid + 256 * j;
        a[j] = alpha[s4];
        b[j] = 1.0f - a[j];
        h[j] = h_a_start[(size_t)k * S4 + s4];
        v[j] = h_v_start[(size_t)k * S4 + s4];   // >= 0 (clamped in kA)
    }

    const vf4* xp   = x + (size_t)k * L * D4 + d4;
    vf4*       orow = out + (size_t)k * L * OSTRIDE4;

    for (int i = 0; i < L; ++i) {
        vf4 xv = xp[(size_t)i * D4];
#pragma unroll
        for (int j = 0; j < 4; ++j) {
            vf4 dx  = xv - h[j];         // uses OLD h (matches reference)
            vf4 adx = a[j] * dx;
            v[j] = b[j] * (v[j] + adx * dx);
            h[j] = h[j] + adx;
            vf4 r;
#pragma unroll
            for (int jj = 0; jj < 4; ++jj) r[jj] = fast_sqrt(v[j][jj]);
            orow[tid + 256 * j]        = h[j];   // avg half of the row
            orow[1024 + tid + 256 * j] = r;      // sd  half of the row
        }
        orow += OSTRIDE4;                // next 32 KB time-row
    }
}

// ---------------------------------------------------------------------------
extern "C" void kernel_launch(void* const* d_in, const int* in_sizes, int n_in,
                              void* d_out, int out_size, void* d_ws, size_t ws_size,
                              hipStream_t stream) {
    const vf4* x     = (const vf4*)d_in[0];   // (T, D) fp32
    const vf4* h_a0  = (const vf4*)d_in[1];   // (N, D)
    const vf4* h_sd0 = (const vf4*)d_in[2];   // (N, D)
    const vf4* alpha = (const vf4*)d_in[3];   // (N, D)
    float* out = (float*)d_out;               // (T,2N,D) + hN_a (N,D) + hN_sd (N,D)
    float* ws  = (float*)d_ws;

    // workspace: 2 arrays of K*S floats = 4 MB each (8 MB total)
    vf4* h_a_start = (vf4*)(ws + 0 * (size_t)K * S);
    vf4* h_v_start = (vf4*)(ws + 1 * (size_t)K * S);

    dim3 blk(256);

    kA_sumscan<<<dim3(S4 / COLS), blk, 0, stream>>>(x, h_a0, h_sd0, alpha,
                                                    h_a_start, h_v_start, out);
    k3_rows<<<dim3(K), blk, 0, stream>>>(x, alpha, h_a_start, h_v_start,
                                         (vf4*)out);
}